// Round 5
// baseline (173.544 us; speedup 1.0000x reference)
//
#include <hip/hip_runtime.h>
#include <hip/hip_bf16.h>
#include <math.h>

#define E_N 4096
#define PI_F 3.14159265358979323846f
#define ATH 0.08726646259971647f   /* radians(5.0) */

// distance histogram: 2048 bins over [0,160); quantiles interpolated in-bin
#define NB1 2048
#define SCALE1 12.8f
#define W1 0.078125f
#define SUMSC 16384.0f             /* fixed-point scale 2^14 for per-pair d */
#define MASK44 ((1ull << 44) - 1ull)

// tiling: upper-triangle 128x128 pair tiles -> 528 blocks
#define TILE 128
#define NT   (E_N / TILE)           /* 32 */
#define NBLK (NT * (NT + 1) / 2)    /* 528 */
#define THR1 512                    /* 8 waves: 528*8=4224 waves, all resident */
#define THR2 1024

// hierarchical hist: 16 global copies, hits go DIRECTLY to global atomics
// (no LDS hist: ~917 hits/block vs 2048-bin zero+merge; frees the DS pipe)
#define N_HIST 16

// workspace layout (bytes): hists zeroed by a 256KB memset graph node
#define O_H1  0                     /* N_HIST x 2048 u64 packed (cnt<<44)|sum14 */
#define ZBYTES (N_HIST * NB1 * 8)   /* 262144 */

// ---- K1: tiled all-pairs -> direct global hist atomics. No fences. --------
__global__ __launch_bounds__(THR1) void pair_hist(const void* __restrict__ posv,
                                                  const int* __restrict__ eidx,
                                                  char* __restrict__ ws)
{
    unsigned long long* h1 = (unsigned long long*)(ws + O_H1);

    __shared__ float4 rowA[TILE];             // (ang, nx, ny, c)  : 2KB
    __shared__ float4 colA[TILE];             // (ang, mx, my, 0)  : 2KB
    __shared__ unsigned s_flag;

    int tid = threadIdx.x, bid = blockIdx.x;

    // decode triangular tile index -> (tr, tc), tr <= tc (uniform scalar loop)
    int tr = 0, rem = bid;
    while (rem >= NT - tr) { rem -= NT - tr; ++tr; }
    int tc = tr + rem;

    if (tid == 0) s_flag = 0u;
    __syncthreads();

    // dtype detect: f32 misread as bf16 halves shows exponents >=137 (|v|>=1024)
    {
        const unsigned short* ph = (const unsigned short*)posv;
        unsigned f = 0;
#pragma unroll
        for (int k = 0; k < 16; ++k) {
            unsigned short v = ph[tid + k * THR1];   // covers first 8192 halves
            if (((v >> 7) & 0xFFu) >= 137u) f = 1u;
        }
        if (f) atomicOr(&s_flag, 1u);
    }
    __syncthreads();
    bool isf32 = (s_flag != 0u);

    // geometry for this tile's 128 row edges + 128 col edges (1 edge/thread)
    if (tid < 2 * TILE) {
        bool isCol = tid < TILE;
        int local = isCol ? tid : tid - TILE;
        int e = (isCol ? tc : tr) * TILE + local;
        int s = eidx[e], d2 = eidx[E_N + e];
        float px, py, qx, qy;
        if (isf32) {
            const float* pf = (const float*)posv;
            px = pf[2*s]; py = pf[2*s+1]; qx = pf[2*d2]; qy = pf[2*d2+1];
        } else {
            const __hip_bfloat16* pb = (const __hip_bfloat16*)posv;
            px = __bfloat162float(pb[2*s]); py = __bfloat162float(pb[2*s+1]);
            qx = __bfloat162float(pb[2*d2]); qy = __bfloat162float(pb[2*d2+1]);
        }
        float vx = qx - px, vy = qy - py;
        float len = fmaxf(sqrtf(vx*vx + vy*vy), 1e-8f);
        float dx = vx / len, dy = vy / len;
        float a = fmodf(atan2f(dy, dx), PI_F);
        if (a < 0.0f) a += PI_F;              // python floor-mod -> [0, pi)
        if (isCol) colA[local] = make_float4(a, (px + qx) * 0.5f, (py + qy) * 0.5f, 0.0f);
        else       rowA[local] = make_float4(a, -dy, dx, px * (-dy) + py * dx);
    }
    __syncthreads();

    // 128x128 pair tile: thread -> (row = tid&127, col 32-slice = tid>>7)
    // wave lanes share the col index -> colA reads are LDS broadcasts
    {
        int r = tid & (TILE - 1);
        int q = tid >> 7;                     // 0..3
        float4 rg = rowA[r];
        float angp = rg.x, nx = rg.y, ny = rg.z, c = rg.w;
        int j0 = q * 32;
        bool diag = (tr == tc);
        // copy select mixes bid and q so concurrent thread-groups spread
        unsigned long long* myh =
            h1 + (unsigned)(((bid << 2) | q) & (N_HIST - 1)) * NB1;
#pragma unroll 4
        for (int jj = 0; jj < 32; ++jj) {
            int j = j0 + jj;
            if (diag && j <= r) continue;     // strict i<j on diagonal tiles
            float4 cg = colA[j];
            float da = fabsf(angp - cg.x);
            float circ = fminf(da, PI_F - da);
            if (circ <= ATH) {
                float d = fabsf(nx * cg.y + ny * cg.z - c);
                int b = (int)(d * SCALE1); if (b > NB1 - 1) b = NB1 - 1;
                // fire-and-forget packed u64: count in [63:44], sum14 in [43:0]
                atomicAdd(&myh[b],
                          (1ull << 44) | (unsigned long long)(d * SUMSC + 0.5f));
            }
        }
    }
}

// ---- K2: 1 block. Sum 16 copies, scan, interpolate quantiles, hinge. ------
__global__ __launch_bounds__(THR2) void reduce_ep(const char* __restrict__ ws,
                                                  unsigned* __restrict__ out)
{
    const unsigned long long* h1 = (const unsigned long long*)(ws + O_H1);

    __shared__ unsigned s_scan[THR2];         // scan : 4KB
    __shared__ float   s_vv[3];
    __shared__ float   s_lohi[2];
    __shared__ double  s_dw[THR2 / 64];

    int tid = threadIdx.x;
    int w = tid >> 6, lane = tid & 63;

    // exact integer sum of the 16 hist copies (packed fields cannot carry:
    // cnt <= 2^20 in bits [63:44], sum14 <= ~2^33 in bits [43:0])
    unsigned long long v0 = 0ull, v1 = 0ull;
    {
        const ulonglong2* hv = (const ulonglong2*)h1;
#pragma unroll
        for (int c = 0; c < N_HIST; ++c) {
            ulonglong2 p = hv[c * (NB1 / 2) + tid];   // bins 2tid, 2tid+1 of copy c
            v0 += p.x; v1 += p.y;
        }
    }
    unsigned g0, g1; double S0, S1;
    g0 = (unsigned)(v0 >> 44); g1 = (unsigned)(v1 >> 44);
    S0 = (double)(v0 & MASK44) * (1.0 / 16384.0);
    S1 = (double)(v1 & MASK44) * (1.0 / 16384.0);
    unsigned gs = g0 + g1;
    s_scan[tid] = gs;
    __syncthreads();
    for (int off = 1; off < THR2; off <<= 1) {
        unsigned v = (tid >= off) ? s_scan[tid - off] : 0u;
        __syncthreads();
        s_scan[tid] += v;
        __syncthreads();
    }
    unsigned n = s_scan[THR2 - 1];
    if (n == 0) {
        if (tid == 0) {
            __hip_bfloat16 h = __float2bfloat16(0.0f);
            unsigned short b = *(unsigned short*)&h;
            out[0] = ((unsigned)b << 16) | (unsigned)b;
        }
        return;
    }
    long long q1i = (long long)(n / 4) - 1; if (q1i < 0) q1i = 0;
    long long q3i = (3LL * (long long)n) / 4;
    if (q3i > (long long)n - 1) q3i = (long long)n - 1;
    unsigned rks[3] = { (unsigned)q1i, n / 2, (unsigned)q3i };
    unsigned excl = s_scan[tid] - gs;
    unsigned gl[2] = { g0, g1 };
    for (int t = 0; t < 3; ++t) {
        unsigned r = rks[t];
        if (r >= excl && r < excl + gs) {
            unsigned cum = excl;
#pragma unroll
            for (int k = 0; k < 2; ++k) {
                unsigned c2 = cum + gl[k];
                if (r < c2) {
                    int b = 2 * tid + k;
                    float rr = (float)(r - cum);
                    // uniform-within-bin interpolated quantile value
                    s_vv[t] = ((float)b + (rr + 0.5f) / (float)gl[k]) * W1;
                    break;
                }
                cum = c2;
            }
        }
    }
    __syncthreads();
    if (tid == 0) {
        float iqr = fmaxf(s_vv[2] - s_vv[0], 1e-6f);
        float mu = s_vv[1];
        float margin = 0.75f * iqr;        // iqr * 0.5 * 1.5
        s_lohi[0] = mu - margin;
        s_lohi[1] = mu + margin;
    }
    __syncthreads();
    float lo = s_lohi[0], hi = s_lohi[1];
    // hinge from (count,sum) per bin; boundary bins via uniform integral
    double H = 0.0;
#pragma unroll
    for (int k = 0; k < 2; ++k) {
        int b = 2 * tid + k;
        unsigned c = gl[k];
        if (!c) continue;
        double S = k ? S1 : S0;
        float blo = (float)b * W1, bhi = blo + W1;
        if (bhi <= lo) {
            H += (double)lo * (double)c - S;
        } else if (blo >= hi) {
            H += S - (double)hi * (double)c;
        } else {
            double cf = (double)c / (double)W1;
            if (blo < lo) {
                float u1 = fminf(bhi, lo);
                double a0 = (double)lo - (double)blo;
                double a1 = (double)lo - (double)u1;
                H += cf * 0.5 * (a0 * a0 - a1 * a1);
            }
            if (bhi > hi) {
                float v0b = fmaxf(blo, hi);
                double b1 = (double)bhi - (double)hi;
                double b0 = (double)v0b - (double)hi;
                H += cf * 0.5 * (b1 * b1 - b0 * b0);
            }
        }
    }
    for (int off = 32; off > 0; off >>= 1) H += __shfl_down(H, off, 64);
    if (lane == 0) s_dw[w] = H;
    __syncthreads();
    if (tid == 0) {
        double tot = 0.0;
        for (int k = 0; k < THR2 / 64; ++k) tot += s_dw[k];
        float loss = (float)(tot / (double)n);
        __hip_bfloat16 h = __float2bfloat16(loss);
        unsigned short b = *(unsigned short*)&h;
        out[0] = ((unsigned)b << 16) | (unsigned)b;   // dtype-hedged scalar write
    }
}

// ============================== launcher ====================================
extern "C" void kernel_launch(void* const* d_in, const int* in_sizes, int n_in,
                              void* d_out, int out_size, void* d_ws, size_t ws_size,
                              hipStream_t stream) {
    const void* pos = d_in[0];
    const int* eidx = (const int*)d_in[2];   // adjacency (d_in[1]) unused
    char* ws = (char*)d_ws;
    unsigned* outp = (unsigned*)d_out;

    hipMemsetAsync(ws, 0, ZBYTES, stream);   // zero 16 packed hists
    pair_hist<<<NBLK, THR1, 0, stream>>>(pos, eidx, ws);
    reduce_ep<<<1, THR2, 0, stream>>>(ws, outp);
}

// Round 6
// 110.741 us; speedup vs baseline: 1.5671x; 1.5671x over previous
//
#include <hip/hip_runtime.h>
#include <hip/hip_bf16.h>
#include <math.h>

#define E_N 4096
#define PI_F 3.14159265358979323846f
#define ATH 0.08726646259971647f   /* radians(5.0) */

// distance histogram: 2048 bins over [0,160); quantiles interpolated in-bin
#define NB1 2048
#define SCALE1 12.8f
#define W1 0.078125f
#define SUMSC 16384.0f             /* fixed-point scale 2^14 for per-pair d */
#define MASK44 ((1ull << 44) - 1ull)

// tiling: upper-triangle 128x128 pair tiles -> 528 blocks
#define TILE 128
#define NT   (E_N / TILE)           /* 32 */
#define NBLK (NT * (NT + 1) / 2)    /* 528 */
#define THR1 512                    /* 20.6KB LDS -> 4 blocks/CU resident ->
                                       all 528 blocks in ONE scheduling round */
#define THR2 1024

// hierarchical merge: 16 global hist copies (round-5 lesson: per-hit device
// atomics bypass non-coherent per-XCD L2 -> 80us; LDS hist + dense merge wins)
#define N_HIST 16

// workspace layout (bytes): hists zeroed by a 256KB memset graph node
#define O_H1  0                     /* N_HIST x 2048 u64 packed (cnt<<44)|sum14 */
#define ZBYTES (N_HIST * NB1 * 8)   /* 262144 */

// ---- K1: tiled all-pairs -> LDS hist -> dense merge. No fences/tickets. ---
__global__ __launch_bounds__(THR1) void pair_hist(const void* __restrict__ posv,
                                                  const int* __restrict__ eidx,
                                                  char* __restrict__ ws)
{
    unsigned long long* h1 = (unsigned long long*)(ws + O_H1);

    __shared__ float4 rowA[TILE];             // (ang, nx, ny, c)  : 2KB
    __shared__ float4 colA[TILE];             // (ang, mx, my, 0)  : 2KB
    __shared__ unsigned long long s_s64[NB1]; // packed hist       : 16KB
    __shared__ unsigned s_flag;

    int tid = threadIdx.x, bid = blockIdx.x;

    // decode triangular tile index -> (tr, tc), tr <= tc (uniform scalar loop)
    int tr = 0, rem = bid;
    while (rem >= NT - tr) { rem -= NT - tr; ++tr; }
    int tc = tr + rem;

    if (tid == 0) s_flag = 0u;
    for (int k = tid; k < NB1; k += THR1) s_s64[k] = 0ull;
    __syncthreads();

    // dtype detect: f32 misread as bf16 halves shows exponents >=137 (|v|>=1024)
    {
        const unsigned short* ph = (const unsigned short*)posv;
        unsigned f = 0;
#pragma unroll
        for (int k = 0; k < 16; ++k) {
            unsigned short v = ph[tid + k * THR1];   // first 8192 halves
            if (((v >> 7) & 0xFFu) >= 137u) f = 1u;
        }
        if (f) atomicOr(&s_flag, 1u);
    }
    __syncthreads();
    bool isf32 = (s_flag != 0u);

    // geometry for this tile's 128 row edges + 128 col edges (1 edge/thread)
    if (tid < 2 * TILE) {
        bool isCol = tid < TILE;
        int local = isCol ? tid : tid - TILE;
        int e = (isCol ? tc : tr) * TILE + local;
        int s = eidx[e], d2 = eidx[E_N + e];
        float px, py, qx, qy;
        if (isf32) {
            const float* pf = (const float*)posv;
            px = pf[2*s]; py = pf[2*s+1]; qx = pf[2*d2]; qy = pf[2*d2+1];
        } else {
            const __hip_bfloat16* pb = (const __hip_bfloat16*)posv;
            px = __bfloat162float(pb[2*s]); py = __bfloat162float(pb[2*s+1]);
            qx = __bfloat162float(pb[2*d2]); qy = __bfloat162float(pb[2*d2+1]);
        }
        float vx = qx - px, vy = qy - py;
        float len = fmaxf(sqrtf(vx*vx + vy*vy), 1e-8f);
        float dx = vx / len, dy = vy / len;
        float a = fmodf(atan2f(dy, dx), PI_F);
        if (a < 0.0f) a += PI_F;              // python floor-mod -> [0, pi)
        if (isCol) colA[local] = make_float4(a, (px + qx) * 0.5f, (py + qy) * 0.5f, 0.0f);
        else       rowA[local] = make_float4(a, -dy, dx, px * (-dy) + py * dx);
    }
    __syncthreads();

    // 128x128 pair tile: thread -> (row = tid&127, col 32-slice = tid>>7)
    // wave lanes share the col index -> colA reads are LDS broadcasts
    {
        int r = tid & (TILE - 1);
        int q = tid >> 7;                     // 0..3
        float4 rg = rowA[r];
        float angp = rg.x, nx = rg.y, ny = rg.z, c = rg.w;
        int j0 = q * 32;
        bool diag = (tr == tc);
#pragma unroll 4
        for (int jj = 0; jj < 32; ++jj) {
            int j = j0 + jj;
            if (diag && j <= r) continue;     // strict i<j on diagonal tiles
            float4 cg = colA[j];
            float da = fabsf(angp - cg.x);
            float circ = fminf(da, PI_F - da);
            if (circ <= ATH) {
                float d = fabsf(nx * cg.y + ny * cg.z - c);
                int b = (int)(d * SCALE1); if (b > NB1 - 1) b = NB1 - 1;
                // single packed LDS atomic: count in [63:44], sum14 in [43:0]
                atomicAdd(&s_s64[b],
                          (1ull << 44) | (unsigned long long)(d * SUMSC + 0.5f));
            }
        }
    }
    __syncthreads();

    // merge: ONE dense fire-and-forget u64 atomic per nonzero bin, then exit.
    {
        unsigned long long* myh = h1 + (unsigned)(bid & (N_HIST - 1)) * NB1;
        for (int k = tid; k < NB1; k += THR1) {
            unsigned long long v = s_s64[k];
            if (v) atomicAdd(&myh[k], v);
        }
    }
}

// ---- K2: 1 block. Sum 16 copies, scan, interpolate quantiles, hinge. ------
__global__ __launch_bounds__(THR2) void reduce_ep(const char* __restrict__ ws,
                                                  unsigned* __restrict__ out)
{
    const unsigned long long* h1 = (const unsigned long long*)(ws + O_H1);

    __shared__ unsigned s_scan[THR2];         // scan : 4KB
    __shared__ float   s_vv[3];
    __shared__ float   s_lohi[2];
    __shared__ double  s_dw[THR2 / 64];

    int tid = threadIdx.x;
    int w = tid >> 6, lane = tid & 63;

    // exact integer sum of the 16 hist copies (packed fields cannot carry:
    // cnt <= 2^20 in bits [63:44], sum14 <= ~2^33 in bits [43:0])
    unsigned long long v0 = 0ull, v1 = 0ull;
    {
        const ulonglong2* hv = (const ulonglong2*)h1;
#pragma unroll
        for (int c = 0; c < N_HIST; ++c) {
            ulonglong2 p = hv[c * (NB1 / 2) + tid];   // bins 2tid, 2tid+1 of copy c
            v0 += p.x; v1 += p.y;
        }
    }
    unsigned g0, g1; double S0, S1;
    g0 = (unsigned)(v0 >> 44); g1 = (unsigned)(v1 >> 44);
    S0 = (double)(v0 & MASK44) * (1.0 / 16384.0);
    S1 = (double)(v1 & MASK44) * (1.0 / 16384.0);
    unsigned gs = g0 + g1;
    s_scan[tid] = gs;
    __syncthreads();
    for (int off = 1; off < THR2; off <<= 1) {
        unsigned v = (tid >= off) ? s_scan[tid - off] : 0u;
        __syncthreads();
        s_scan[tid] += v;
        __syncthreads();
    }
    unsigned n = s_scan[THR2 - 1];
    if (n == 0) {
        if (tid == 0) {
            __hip_bfloat16 h = __float2bfloat16(0.0f);
            unsigned short b = *(unsigned short*)&h;
            out[0] = ((unsigned)b << 16) | (unsigned)b;
        }
        return;
    }
    long long q1i = (long long)(n / 4) - 1; if (q1i < 0) q1i = 0;
    long long q3i = (3LL * (long long)n) / 4;
    if (q3i > (long long)n - 1) q3i = (long long)n - 1;
    unsigned rks[3] = { (unsigned)q1i, n / 2, (unsigned)q3i };
    unsigned excl = s_scan[tid] - gs;
    unsigned gl[2] = { g0, g1 };
    for (int t = 0; t < 3; ++t) {
        unsigned r = rks[t];
        if (r >= excl && r < excl + gs) {
            unsigned cum = excl;
#pragma unroll
            for (int k = 0; k < 2; ++k) {
                unsigned c2 = cum + gl[k];
                if (r < c2) {
                    int b = 2 * tid + k;
                    float rr = (float)(r - cum);
                    // uniform-within-bin interpolated quantile value
                    s_vv[t] = ((float)b + (rr + 0.5f) / (float)gl[k]) * W1;
                    break;
                }
                cum = c2;
            }
        }
    }
    __syncthreads();
    if (tid == 0) {
        float iqr = fmaxf(s_vv[2] - s_vv[0], 1e-6f);
        float mu = s_vv[1];
        float margin = 0.75f * iqr;        // iqr * 0.5 * 1.5
        s_lohi[0] = mu - margin;
        s_lohi[1] = mu + margin;
    }
    __syncthreads();
    float lo = s_lohi[0], hi = s_lohi[1];
    // hinge from (count,sum) per bin; boundary bins via uniform integral
    double H = 0.0;
#pragma unroll
    for (int k = 0; k < 2; ++k) {
        int b = 2 * tid + k;
        unsigned c = gl[k];
        if (!c) continue;
        double S = k ? S1 : S0;
        float blo = (float)b * W1, bhi = blo + W1;
        if (bhi <= lo) {
            H += (double)lo * (double)c - S;
        } else if (blo >= hi) {
            H += S - (double)hi * (double)c;
        } else {
            double cf = (double)c / (double)W1;
            if (blo < lo) {
                float u1 = fminf(bhi, lo);
                double a0 = (double)lo - (double)blo;
                double a1 = (double)lo - (double)u1;
                H += cf * 0.5 * (a0 * a0 - a1 * a1);
            }
            if (bhi > hi) {
                float v0b = fmaxf(blo, hi);
                double b1 = (double)bhi - (double)hi;
                double b0 = (double)v0b - (double)hi;
                H += cf * 0.5 * (b1 * b1 - b0 * b0);
            }
        }
    }
    for (int off = 32; off > 0; off >>= 1) H += __shfl_down(H, off, 64);
    if (lane == 0) s_dw[w] = H;
    __syncthreads();
    if (tid == 0) {
        double tot = 0.0;
        for (int k = 0; k < THR2 / 64; ++k) tot += s_dw[k];
        float loss = (float)(tot / (double)n);
        __hip_bfloat16 h = __float2bfloat16(loss);
        unsigned short b = *(unsigned short*)&h;
        out[0] = ((unsigned)b << 16) | (unsigned)b;   // dtype-hedged scalar write
    }
}

// ============================== launcher ====================================
extern "C" void kernel_launch(void* const* d_in, const int* in_sizes, int n_in,
                              void* d_out, int out_size, void* d_ws, size_t ws_size,
                              hipStream_t stream) {
    const void* pos = d_in[0];
    const int* eidx = (const int*)d_in[2];   // adjacency (d_in[1]) unused
    char* ws = (char*)d_ws;
    unsigned* outp = (unsigned*)d_out;

    hipMemsetAsync(ws, 0, ZBYTES, stream);   // zero 16 packed hists
    pair_hist<<<NBLK, THR1, 0, stream>>>(pos, eidx, ws);
    reduce_ep<<<1, THR2, 0, stream>>>(ws, outp);
}